// Round 1
// baseline (436.020 us; speedup 1.0000x reference)
//
#include <hip/hip_runtime.h>

// MXFP8 E4M3 quantize-dequantize (microxcaling semantics), fp32 -> fp32.
// BLOCK_SIZE=32 along last axis, EMAX=8, MBITS=5 (3 mantissa bits), MAX_NORM=448.
// Bit-exact vs reference: floor(log2) via exponent-field extraction (clamps
// make denorm/zero cases coincide), power-of-two scales via v_ldexp_f32
// (exact), round-half-away-from-zero via floor(|v|+0.5) with |v|<16 (exact).
//
// R4: memory-bound launch shape (Guideline 11).
//   - grid capped at 2048 blocks (8 blocks/CU), grid-stride loop.
//   - 4-deep batched nontemporal loads per iteration (4 KB in flight per
//     wave instead of 1 KB), compute, then 4 batched stores.
//   - 32 float4 per thread amortizes block dispatch 32x vs the previous
//     one-float4-per-thread 65,536-block launch.
// DPP group validity: T = gridDim*blockDim is a multiple of 8 and lane i
// reads float4 index (8-aligned base + i), so each 8-lane DPP group still
// covers exactly one 32-element MX block at every unroll step.

typedef float vfloat4 __attribute__((ext_vector_type(4)));

template <int CTRL>
__device__ __forceinline__ float dpp_max(float x) {
    int partner = __builtin_amdgcn_update_dpp(
        0, __float_as_int(x), CTRL, 0xF, 0xF, true);
    return fmaxf(x, __int_as_float(partner));
}

__device__ __forceinline__ float mx_quant_elem(float x, int sh) {
    // a = x / 2^sh  (exact: power-of-two scale)
    float a = ldexpf(x, -sh);
    // private exponent: floor(log2(|a|)), clamped to MIN_EXP = -6
    int pe = (int)((__float_as_uint(a) >> 23) & 0xFFu) - 127;
    pe = (pe < -6) ? -6 : pe;
    // put the 3 mantissa bits into the integer part: v = a * 2^(3-pe)
    float v = ldexpf(a, 3 - pe);
    // round to nearest, half away from zero (|v| < 16 so +0.5/floor exact)
    float r = copysignf(floorf(fabsf(v) + 0.5f), v);
    // back to block-scaled domain, saturate to e4m3 max normal, dequantize
    float q = ldexpf(r, pe - 3);
    q = fminf(fmaxf(q, -448.0f), 448.0f);
    return ldexpf(q, sh);
}

__device__ __forceinline__ vfloat4 mx_quant_vec(vfloat4 d) {
    // 32-elem MX block = 8 consecutive lanes x float4.
    // Lane-local amax, then 8-lane max via 3 DPP ops (all-VALU):
    //   0xB1 = quad_perm [1,0,3,2]  (xor 1)
    //   0x4E = quad_perm [2,3,0,1]  (xor 2)
    //   0x141 = row_half_mirror     (xor 7 -> crosses the two quads;
    //           valid because each lane already holds its quad-max)
    float m = fmaxf(fmaxf(fabsf(d.x), fabsf(d.y)), fmaxf(fabsf(d.z), fabsf(d.w)));
    m = dpp_max<0xB1>(m);
    m = dpp_max<0x4E>(m);
    m = dpp_max<0x141>(m);

    // shared exponent: floor(log2(amax)) - EMAX, clamped to >= -127.
    // (m >= 0 so the exponent field alone suffices; amax==0 -> fl=-127,
    // matching the reference's clamp path.)
    int fl = (int)(__float_as_uint(m) >> 23) - 127;
    int sh = fl - 8;
    sh = (sh < -127) ? -127 : sh;
    // overflow->NaN branch (shared_exp > 127) unreachable for finite fp32.

    vfloat4 r;
    r.x = mx_quant_elem(d.x, sh);
    r.y = mx_quant_elem(d.y, sh);
    r.z = mx_quant_elem(d.z, sh);
    r.w = mx_quant_elem(d.w, sh);
    return r;
}

__global__ __launch_bounds__(256) void mx_quantize_kernel(
        const vfloat4* __restrict__ in, vfloat4* __restrict__ out, int n4) {
    const int T = gridDim.x * blockDim.x;   // total threads, multiple of 8
    int i = blockIdx.x * blockDim.x + threadIdx.x;

    // Main loop: 4 float4 per thread per iteration; batch all 4 loads
    // before any compute so 4 vmem ops are in flight per wave.
    for (; i + 3 * T < n4; i += 4 * T) {
        vfloat4 d0 = __builtin_nontemporal_load(&in[i]);
        vfloat4 d1 = __builtin_nontemporal_load(&in[i + T]);
        vfloat4 d2 = __builtin_nontemporal_load(&in[i + 2 * T]);
        vfloat4 d3 = __builtin_nontemporal_load(&in[i + 3 * T]);
        d0 = mx_quant_vec(d0);
        d1 = mx_quant_vec(d1);
        d2 = mx_quant_vec(d2);
        d3 = mx_quant_vec(d3);
        __builtin_nontemporal_store(d0, &out[i]);
        __builtin_nontemporal_store(d1, &out[i + T]);
        __builtin_nontemporal_store(d2, &out[i + 2 * T]);
        __builtin_nontemporal_store(d3, &out[i + 3 * T]);
    }
    // Remainder (empty for 8192x8192, kept for generality).
    for (; i < n4; i += T) {
        vfloat4 d = __builtin_nontemporal_load(&in[i]);
        __builtin_nontemporal_store(mx_quant_vec(d), &out[i]);
    }
}

extern "C" void kernel_launch(void* const* d_in, const int* in_sizes, int n_in,
                              void* d_out, int out_size, void* d_ws, size_t ws_size,
                              hipStream_t stream) {
    const vfloat4* in = (const vfloat4*)d_in[0];
    vfloat4* out = (vfloat4*)d_out;
    int n4 = in_sizes[0] / 4;   // 16,777,216 float4 work items
    int block = 256;
    int grid = (n4 + block - 1) / block;
    if (grid > 2048) grid = 2048;           // 8 blocks/CU, grid-stride the rest
    mx_quantize_kernel<<<grid, block, 0, stream>>>(in, out, n4);
}

// Round 2
// 407.680 us; speedup vs baseline: 1.0695x; 1.0695x over previous
//
#include <hip/hip_runtime.h>

// MXFP8 E4M3 quantize-dequantize (microxcaling semantics), fp32 -> fp32.
// BLOCK_SIZE=32 along last axis, EMAX=8, MBITS=5 (3 mantissa bits), MAX_NORM=448.
// Bit-exact vs reference: floor(log2) via exponent-field extraction (clamps
// make denorm/zero cases coincide), power-of-two scales via v_ldexp_f32
// (exact), round-half-away-from-zero via floor(|v|+0.5) with |v|<16 (exact).
//
// R5: REVERT to the R0/R3 launch shape. R4's 2048-block grid-stride +
// 4-deep batching regressed the kernel ~78 -> ~106 us (dur_us 408 -> 436):
// with one float4 per thread and 65,536 blocks the dispatcher already
// supplies full memory-level parallelism, and this shape measured
// ~6.9 TB/s effective (at/above the 6.3 TB/s achievable ceiling, partial
// LLC assist). Keep one-float4-per-thread, full grid.

typedef float vfloat4 __attribute__((ext_vector_type(4)));

template <int CTRL>
__device__ __forceinline__ float dpp_max(float x) {
    int partner = __builtin_amdgcn_update_dpp(
        0, __float_as_int(x), CTRL, 0xF, 0xF, true);
    return fmaxf(x, __int_as_float(partner));
}

__device__ __forceinline__ float mx_quant_elem(float x, int sh) {
    // a = x / 2^sh  (exact: power-of-two scale)
    float a = ldexpf(x, -sh);
    // private exponent: floor(log2(|a|)), clamped to MIN_EXP = -6
    int pe = (int)((__float_as_uint(a) >> 23) & 0xFFu) - 127;
    pe = (pe < -6) ? -6 : pe;
    // put the 3 mantissa bits into the integer part: v = a * 2^(3-pe)
    float v = ldexpf(a, 3 - pe);
    // round to nearest, half away from zero (|v| < 16 so +0.5/floor exact)
    float r = copysignf(floorf(fabsf(v) + 0.5f), v);
    // back to block-scaled domain, saturate to e4m3 max normal, dequantize
    float q = ldexpf(r, pe - 3);
    q = fminf(fmaxf(q, -448.0f), 448.0f);
    return ldexpf(q, sh);
}

__global__ __launch_bounds__(256) void mx_quantize_kernel(
        const vfloat4* __restrict__ in, vfloat4* __restrict__ out, int n4) {
    int stride = gridDim.x * blockDim.x;
    for (int tid = blockIdx.x * blockDim.x + threadIdx.x; tid < n4; tid += stride) {
        vfloat4 d = __builtin_nontemporal_load(&in[tid]);

        // 32-elem MX block = 8 consecutive lanes x float4.
        // Lane-local amax, then 8-lane max via 3 DPP ops (all-VALU):
        //   0xB1 = quad_perm [1,0,3,2]  (xor 1)
        //   0x4E = quad_perm [2,3,0,1]  (xor 2)
        //   0x141 = row_half_mirror     (xor 7 -> crosses the two quads;
        //           valid because each lane already holds its quad-max)
        float m = fmaxf(fmaxf(fabsf(d.x), fabsf(d.y)), fmaxf(fabsf(d.z), fabsf(d.w)));
        m = dpp_max<0xB1>(m);
        m = dpp_max<0x4E>(m);
        m = dpp_max<0x141>(m);

        // shared exponent: floor(log2(amax)) - EMAX, clamped to >= -127.
        // (m >= 0 so the exponent field alone suffices; amax==0 -> fl=-127,
        // matching the reference's clamp path.)
        int fl = (int)(__float_as_uint(m) >> 23) - 127;
        int sh = fl - 8;
        sh = (sh < -127) ? -127 : sh;
        // overflow->NaN branch (shared_exp > 127) unreachable for finite fp32.

        d.x = mx_quant_elem(d.x, sh);
        d.y = mx_quant_elem(d.y, sh);
        d.z = mx_quant_elem(d.z, sh);
        d.w = mx_quant_elem(d.w, sh);

        __builtin_nontemporal_store(d, &out[tid]);
    }
}

extern "C" void kernel_launch(void* const* d_in, const int* in_sizes, int n_in,
                              void* d_out, int out_size, void* d_ws, size_t ws_size,
                              hipStream_t stream) {
    const vfloat4* in = (const vfloat4*)d_in[0];
    vfloat4* out = (vfloat4*)d_out;
    int n4 = in_sizes[0] / 4;   // 16,777,216 float4 work items
    int block = 256;
    int grid = (n4 + block - 1) / block;   // 65,536 blocks
    mx_quantize_kernel<<<grid, block, 0, stream>>>(in, out, n4);
}